// Round 3
// baseline (20.842 us; speedup 1.0000x reference)
//
#include <hip/hip_runtime.h>

namespace {
constexpr int R = 16;
constexpr int A = 4;

// Per-rule packed params, one 80-byte struct -> 5x ds_read_b128 broadcast.
// c = (C0_hi, C0_lo, c_sorted[k], c_orig[k])
struct PK { float4 bh, kh, bl, kl, c; };
}

// KM endpoint pass. `right` is compile-time at call sites (inlined).
// eU = C0 + sum_a B_a x_a + K_a x_a^2  (log2e folded; exp2 builtin)
// Scan: cross-multiplied ratio comparisons, num/den latched at argmin/argmax.
__device__ __forceinline__ float km_pass(bool right, const float4 xv, const float4 xq,
                                         const PK* __restrict__ pk)
{
    float d[R], csr[R], cor[R];
    float s0 = 0.f, t0 = 0.f, su = 0.f;
    #pragma unroll
    for (int k = 0; k < R; ++k) {
        const PK q = pk[k];                 // 5x b128, uniform addr -> broadcast
        float eU = q.c.x, eL = q.c.y;
        eU = fmaf(q.bh.x, xv.x, eU); eU = fmaf(q.bh.y, xv.y, eU);
        eU = fmaf(q.bh.z, xv.z, eU); eU = fmaf(q.bh.w, xv.w, eU);
        eU = fmaf(q.kh.x, xq.x, eU); eU = fmaf(q.kh.y, xq.y, eU);
        eU = fmaf(q.kh.z, xq.z, eU); eU = fmaf(q.kh.w, xq.w, eU);
        eL = fmaf(q.bl.x, xv.x, eL); eL = fmaf(q.bl.y, xv.y, eL);
        eL = fmaf(q.bl.z, xv.z, eL); eL = fmaf(q.bl.w, xv.w, eL);
        eL = fmaf(q.kl.x, xq.x, eL); eL = fmaf(q.kl.y, xq.y, eL);
        eL = fmaf(q.kl.z, xq.z, eL); eL = fmaf(q.kl.w, xq.w, eL);
        const float uu = __builtin_amdgcn_exp2f(eU);   // prod_a mu_hi
        const float ll = __builtin_amdgcn_exp2f(eL);   // prod_a mu_lo
        const float w  = right ? uu : ll;
        csr[k] = q.c.z; cor[k] = q.c.w;
        s0 = fmaf(csr[k], w, s0);
        t0 += w;
        su = fmaf(cor[k], w, su);           // reference pairs UNSORTED c with sorted-space selection
        d[k] = right ? (ll - uu) : (uu - ll);
    }
    // k = 0 of the inclusive cumsum
    float ss = fmaf(csr[0], d[0], s0);
    float tt = t0 + d[0];
    float cn = cor[0] * d[0];
    float sb = ss, tb = tt, cnb = cn;
    const float tt0 = tt, cn0 = cn;
    #pragma unroll
    for (int k = 1; k < R; ++k) {
        ss = fmaf(csr[k], d[k], ss);
        tt += d[k];
        cn = fmaf(cor[k], d[k], cn);
        // left:  ratio_k < best  <=>  ss*tb < sb*tt   (tt,tb > 0)
        // right: ratio_k > best  <=>  ss*tb > sb*tt
        const bool take = right ? ((ss * tb) > (sb * tt)) : ((ss * tb) < (sb * tt));
        if (take) { sb = ss; tb = tt; cnb = cn; }        // first occurrence
    }
    // override to k=0 iff q0 dominates: left: q0 <= min_ratio; right: q0 >= max_ratio
    const bool zero = right ? ((s0 * tb) >= (sb * t0)) : ((s0 * tb) <= (sb * t0));
    if (zero) { tb = tt0; cnb = cn0; }
    // den = t0 + sum_{k<=loc} d = tb  (latched); 1-ulp rcp fine at 2.8e-2 tolerance
    return (su + cnb) * __builtin_amdgcn_rcpf(tb);
}

// Fused: every block redundantly computes prep (1 wave, tiny) into LDS,
// then 256 threads process 1 sample each. No second dispatch.
__global__ __launch_bounds__(256) void t2fls_fused(
    const float* __restrict__ x,
    const float* __restrict__ frb,
    const float* __restrict__ c1g,
    const float* __restrict__ c2g,
    float* __restrict__ out)
{
    __shared__ PK    pk[2][R];
    __shared__ float cbuf[2][R];
    __shared__ int   idxs[2][R];
    __shared__ float csort[2][R], corig[2][R];

    const int t = threadIdx.x;
    const int gid = blockIdx.x * 256 + t;

    // issue the sample load early so HBM latency hides under prep
    const float4 xv = reinterpret_cast<const float4*>(x)[gid];

    if (t < 2 * R) {
        const int p = t >> 4, i = t & 15;
        cbuf[p][i] = p ? c2g[i] : c1g[i];
    }
    __syncthreads();
    if (t < 2 * R) {
        const int p = t >> 4, i = t & 15;
        const float ci = cbuf[p][i];
        int rank = 0;
        for (int j = 0; j < R; ++j) {
            const float cj = cbuf[p][j];
            rank += (cj < ci) || (cj == ci && j < i);    // stable argsort
        }
        idxs[p][rank] = i;
        csort[p][rank] = ci;
        corig[p][i]   = ci;
    }
    __syncthreads();
    if (t < 2 * R) {
        const int p = t >> 4, k = t & 15;
        const int i = idxs[p][k];
        const float HL2E = 0.7213475204444817f;          // 0.5*log2(e)
        float c0h = 0.f, c0l = 0.f;
        float bh[A], kh[A], bl[A], kl[A];
        #pragma unroll
        for (int a = 0; a < A; ++a) {
            const float m  = frb[(i * A + a) * 3 + 0];
            const float s1 = frb[(i * A + a) * 3 + 1];
            const float s2 = frb[(i * A + a) * 3 + 2];
            const float slo = fminf(s1, s2), shi = fmaxf(s1, s2);
            const float ku  = -HL2E / (shi * shi);
            const float klv = -HL2E / (slo * slo);
            kh[a] = ku;  bh[a] = -2.f * ku  * m;  c0h = fmaf(ku,  m * m, c0h);
            kl[a] = klv; bl[a] = -2.f * klv * m;  c0l = fmaf(klv, m * m, c0l);
        }
        PK q;
        q.bh = make_float4(bh[0], bh[1], bh[2], bh[3]);
        q.kh = make_float4(kh[0], kh[1], kh[2], kh[3]);
        q.bl = make_float4(bl[0], bl[1], bl[2], bl[3]);
        q.kl = make_float4(kl[0], kl[1], kl[2], kl[3]);
        q.c  = make_float4(c0h, c0l, csort[p][k], corig[p][k]);
        pk[p][k] = q;
    }
    __syncthreads();

    const float4 xq = make_float4(xv.x * xv.x, xv.y * xv.y, xv.z * xv.z, xv.w * xv.w);
    const float left  = km_pass(false, xv, xq, pk[0]);
    const float right = km_pass(true,  xv, xq, pk[1]);
    out[gid] = 0.5f * (left + right);
}

extern "C" void kernel_launch(void* const* d_in, const int* in_sizes, int n_in,
                              void* d_out, int out_size, void* d_ws, size_t ws_size,
                              hipStream_t stream) {
    const float* x   = (const float*)d_in[0];   // (N, 4) float32
    const float* frb = (const float*)d_in[1];   // (R*A*3,) float32
    const float* c1  = (const float*)d_in[2];   // (R,) float32
    const float* c2  = (const float*)d_in[3];   // (R,) float32
    float* out = (float*)d_out;                 // (N,) float32

    const int n = out_size;                     // N = 262144 (multiple of 256)
    const int blocks = n / 256;
    hipLaunchKernelGGL(t2fls_fused, dim3(blocks), dim3(256), 0, stream,
                       x, frb, c1, c2, out);
}